// Round 2
// baseline (1289.204 us; speedup 1.0000x reference)
//
#include <hip/hip_runtime.h>

#define VEC_DIM   300
#define VEC_F4    75          // 300 / 4
#define NUM_WORDS 100000
#define BATCH_N   4096
#define NUM_CTX   10
#define NUM_NOISE 26
#define TWORDS    32

// ===========================================================================
// EXPERIMENT R2: workspace-free path. The rocprof evidence shows 2x ~370us
// fillBufferAligned dispatches (2.4 GB each == ws_size) inside the timed
// region -- 740us of the 809us total. This round tests whether avoiding
// d_ws entirely removes the poison fills from the timed graph.
// ===========================================================================

// ---------------- Direct score kernel (no workspace, no transpose) ---------
// Column gathers of O are scalar stride-400KB reads; O (120MB) + W (120MB)
// are LLC-resident so the ~2GB of line traffic is Infinity-Cache-bound.
__global__ __launch_bounds__(256) void pvdm_score_direct_kernel(
    const int*   __restrict__ context_ids,   // (B, 10)
    const int*   __restrict__ doc_ids,       // (B,)
    const int*   __restrict__ tn_ids,        // (B, 26)
    const float* __restrict__ D,             // (500000, 300)
    const float* __restrict__ W,             // (100000, 300)
    const float* __restrict__ O,             // (300, 100000)
    float*       __restrict__ out)           // (B, 26)
{
    __shared__ __align__(16) float xs[VEC_DIM];
    const int b   = blockIdx.x;
    const int tid = threadIdx.x;

    // x[b] = D[doc] + sum_c W[ctx[c]]  -- 75 threads, float4 each
    if (tid < VEC_F4) {
        const int doc = doc_ids[b];
        float4 v = reinterpret_cast<const float4*>(D + (size_t)doc * VEC_DIM)[tid];
#pragma unroll
        for (int c = 0; c < NUM_CTX; ++c) {
            const int wd = context_ids[b * NUM_CTX + c];
            const float4 u =
                reinterpret_cast<const float4*>(W + (size_t)wd * VEC_DIM)[tid];
            v.x += u.x; v.y += u.y; v.z += u.z; v.w += u.w;
        }
        reinterpret_cast<float4*>(xs)[tid] = v;
    }
    __syncthreads();

    const int wave = tid >> 6;
    const int lane = tid & 63;

    // Each lane's 5 x-values held in registers (d = lane + 64k).
    const float x0 = xs[lane];
    const float x1 = xs[lane + 64];
    const float x2 = xs[lane + 128];
    const float x3 = xs[lane + 192];
    const float x4 = (lane < VEC_DIM - 256) ? xs[lane + 256] : 0.0f;

    const int* __restrict__ tb = tn_ids + b * NUM_NOISE;

    // Preload all t's so the unrolled gather loads are independent (MLP).
    int tv[7];
#pragma unroll
    for (int k = 0; k < 7; ++k) {
        const int n = wave + 4 * k;
        tv[k] = (n < NUM_NOISE) ? tb[n] : tb[0];
    }

#pragma unroll
    for (int k = 0; k < 7; ++k) {
        const int n = wave + 4 * k;
        if (n < NUM_NOISE) {
            const float* __restrict__ col = O + tv[k];
            float s = x0 * col[(size_t)(lane      ) * NUM_WORDS]
                    + x1 * col[(size_t)(lane +  64) * NUM_WORDS]
                    + x2 * col[(size_t)(lane + 128) * NUM_WORDS]
                    + x3 * col[(size_t)(lane + 192) * NUM_WORDS];
            if (lane < VEC_DIM - 256)
                s += x4 * col[(size_t)(lane + 256) * NUM_WORDS];
#pragma unroll
            for (int off = 32; off > 0; off >>= 1)
                s += __shfl_down(s, off, 64);
            if (lane == 0) out[b * NUM_NOISE + n] = s;
        }
    }
}

// ===========================================================================
// Round-1 workspace path kept below (UNUSED this round) for a cheap revert
// if the poison fills turn out to be unconditional.
// ===========================================================================

__global__ __launch_bounds__(256) void transpose_kernel(
    const float* __restrict__ O,   // (300, 100000)
    float*       __restrict__ OT)  // (100000, 300)
{
    __shared__ float tile[TWORDS * VEC_DIM];
    const int wBase = blockIdx.x * TWORDS;
    const int tid   = threadIdx.x;

    for (int idx = tid; idx < VEC_DIM * (TWORDS / 4); idx += 256) {
        const int d = idx >> 3;
        const int c = idx & 7;
        const float4 v = *reinterpret_cast<const float4*>(
            O + (size_t)d * NUM_WORDS + wBase + 4 * c);
        tile[(4 * c + 0) * VEC_DIM + d] = v.x;
        tile[(4 * c + 1) * VEC_DIM + d] = v.y;
        tile[(4 * c + 2) * VEC_DIM + d] = v.z;
        tile[(4 * c + 3) * VEC_DIM + d] = v.w;
    }
    __syncthreads();

    for (int idx = tid; idx < TWORDS * VEC_F4; idx += 256) {
        const int w = idx / VEC_F4;
        const int c = idx - w * VEC_F4;
        const float4 v = *reinterpret_cast<const float4*>(tile + w * VEC_DIM + 4 * c);
        *reinterpret_cast<float4*>(OT + (size_t)(wBase + w) * VEC_DIM + 4 * c) = v;
    }
}

__global__ __launch_bounds__(256) void pvdm_score_kernel(
    const int*   __restrict__ context_ids,
    const int*   __restrict__ doc_ids,
    const int*   __restrict__ tn_ids,
    const float* __restrict__ D,
    const float* __restrict__ W,
    const float* __restrict__ OT,            // (100000, 300)
    float*       __restrict__ out)
{
    __shared__ float4 xs4[VEC_F4];
    const int b   = blockIdx.x;
    const int tid = threadIdx.x;

    if (tid < VEC_F4) {
        const int doc = doc_ids[b];
        float4 v = reinterpret_cast<const float4*>(D + (size_t)doc * VEC_DIM)[tid];
#pragma unroll
        for (int c = 0; c < NUM_CTX; ++c) {
            const int wd = context_ids[b * NUM_CTX + c];
            const float4 u =
                reinterpret_cast<const float4*>(W + (size_t)wd * VEC_DIM)[tid];
            v.x += u.x; v.y += u.y; v.z += u.z; v.w += u.w;
        }
        xs4[tid] = v;
    }
    __syncthreads();

    const int wave = tid >> 6;
    const int lane = tid & 63;

    const float4 xa = xs4[lane];
    float4 xb = make_float4(0.f, 0.f, 0.f, 0.f);
    if (lane < VEC_F4 - 64) xb = xs4[64 + lane];

    const int* __restrict__ tb = tn_ids + b * NUM_NOISE;

#pragma unroll
    for (int k = 0; k < 7; ++k) {
        const int n = wave + 4 * k;
        if (n < NUM_NOISE) {
            const int t = tb[n];
            const float4* __restrict__ row =
                reinterpret_cast<const float4*>(OT + (size_t)t * VEC_DIM);
            const float4 ra = row[lane];
            float s = ra.x * xa.x + ra.y * xa.y + ra.z * xa.z + ra.w * xa.w;
            if (lane < VEC_F4 - 64) {
                const float4 rb = row[64 + lane];
                s += rb.x * xb.x + rb.y * xb.y + rb.z * xb.z + rb.w * xb.w;
            }
#pragma unroll
            for (int off = 32; off > 0; off >>= 1)
                s += __shfl_down(s, off, 64);
            if (lane == 0) out[b * NUM_NOISE + n] = s;
        }
    }
}

extern "C" void kernel_launch(void* const* d_in, const int* in_sizes, int n_in,
                              void* d_out, int out_size, void* d_ws, size_t ws_size,
                              hipStream_t stream) {
    const int*   context_ids = (const int*)  d_in[0];
    const int*   doc_ids     = (const int*)  d_in[1];
    const int*   tn_ids      = (const int*)  d_in[2];
    const float* D           = (const float*)d_in[3];
    const float* W           = (const float*)d_in[4];
    const float* O           = (const float*)d_in[5];
    float*       out         = (float*)d_out;

    // R2 experiment: never touch d_ws -- test whether the 2x ~370us poison
    // fills (2.4 GB each) disappear from the timed region.
    (void)d_ws; (void)ws_size;
    pvdm_score_direct_kernel<<<BATCH_N, 256, 0, stream>>>(
        context_ids, doc_ids, tn_ids, D, W, O, out);
}

// Round 3
// 804.623 us; speedup vs baseline: 1.6022x; 1.6022x over previous
//
#include <hip/hip_runtime.h>

#define VEC_DIM   300
#define VEC_F4    75          // 300 / 4
#define NUM_DOCS  500000
#define NUM_WORDS 100000
#define BATCH_N   4096
#define NUM_CTX   10
#define NUM_NOISE 26

// ---- word-centric pipeline params ----
#define WB        32                      // words per O-chunk
#define NCHUNK    (NUM_WORDS / WB)        // 3125 (exact)
#define CAP       192                     // bucket capacity (lambda=34, >15 sigma)

// ws layout (word-centric path, ~11 MB of the 2.4 GB ws):
//   [0)            X        4096*300 f32   = 4.915 MB
//   [8 MB)         counters NCHUNK i32     = 12.5 KB
//   [8 MB + 64KB)  buckets  NCHUNK*CAP u32 = 2.4 MB
#define WS_X_OFF        0
#define WS_CNT_OFF      (8u << 20)
#define WS_BKT_OFF      ((8u << 20) + (64u << 10))
#define WS_NEEDED       (WS_BKT_OFF + (size_t)NCHUNK * CAP * 4)

// ---------------- zero the per-chunk counters ------------------------------
__global__ __launch_bounds__(256) void zero_counters_kernel(int* __restrict__ cnt)
{
    const int i = blockIdx.x * 256 + threadIdx.x;
    if (i < NCHUNK) cnt[i] = 0;
}

// ---------------- build X rows + scatter (b,n,t) into word-chunk buckets ---
// block = b. tid<75: X[b] = D[doc] + sum_c W[ctx] (float4 per thread).
// tid in [75, 75+26): bucket this b's noise ids.
__global__ __launch_bounds__(128) void build_scatter_kernel(
    const int*   __restrict__ context_ids,   // (B, 10)
    const int*   __restrict__ doc_ids,       // (B,)
    const int*   __restrict__ tn_ids,        // (B, 26)
    const float* __restrict__ D,             // (500000, 300)
    const float* __restrict__ W,             // (100000, 300)
    float*       __restrict__ X,             // (B, 300)
    int*         __restrict__ counters,      // (NCHUNK,)
    unsigned*    __restrict__ buckets)       // (NCHUNK, CAP)
{
    const int b   = blockIdx.x;
    const int tid = threadIdx.x;

    if (tid < VEC_F4) {
        const int doc = doc_ids[b];
        float4 v = reinterpret_cast<const float4*>(D + (size_t)doc * VEC_DIM)[tid];
#pragma unroll
        for (int c = 0; c < NUM_CTX; ++c) {
            const int wd = context_ids[b * NUM_CTX + c];
            const float4 u =
                reinterpret_cast<const float4*>(W + (size_t)wd * VEC_DIM)[tid];
            v.x += u.x; v.y += u.y; v.z += u.z; v.w += u.w;
        }
        reinterpret_cast<float4*>(X + (size_t)b * VEC_DIM)[tid] = v;
    } else if (tid < VEC_F4 + NUM_NOISE) {
        const int n = tid - VEC_F4;
        const int t = tn_ids[b * NUM_NOISE + n];
        const int chunk = t >> 5;               // t / WB
        const int tc    = t & (WB - 1);
        const int pos   = atomicAdd(&counters[chunk], 1);
        if (pos < CAP)                           // never hit at lambda=34; OOB guard
            buckets[(size_t)chunk * CAP + pos] =
                ((unsigned)b << 10) | ((unsigned)n << 5) | (unsigned)tc;
    }
}

// ---------------- per-chunk score kernel -----------------------------------
// block = word chunk. Loads O[0:300][w0:w0+32] coalesced (float4) into LDS
// exactly once, then each wave handles pairs p = wave, wave+4, ...
// LDS tile[word][d]: dot reads are lane-consecutive in d -> conflict-free.
__global__ __launch_bounds__(256) void chunk_score_kernel(
    const float*    __restrict__ O,          // (300, 100000)
    const float*    __restrict__ X,          // (B, 300)
    const int*      __restrict__ counters,   // (NCHUNK,)
    const unsigned* __restrict__ buckets,    // (NCHUNK, CAP)
    float*          __restrict__ out)        // (B, 26)
{
    __shared__ float tile[WB][VEC_DIM];      // 38.4 KB -> 4 blocks/CU
    const int chunk = blockIdx.x;
    const int tid   = threadIdx.x;
    const int w0    = chunk * WB;

    int cnt = counters[chunk];
    if (cnt > CAP) cnt = CAP;

    // Load O chunk: 8 float4-lanes per d-row (32 words = 128 B), 32 rows/pass.
#pragma unroll
    for (int k = 0; k < 10; ++k) {
        const int d  = (tid >> 3) + (k << 5);
        const int jj = tid & 7;
        if (d < VEC_DIM) {
            const float4 v = *reinterpret_cast<const float4*>(
                O + (size_t)d * NUM_WORDS + w0 + 4 * jj);
            tile[4 * jj + 0][d] = v.x;
            tile[4 * jj + 1][d] = v.y;
            tile[4 * jj + 2][d] = v.z;
            tile[4 * jj + 3][d] = v.w;
        }
    }
    __syncthreads();

    const int wave = tid >> 6;
    const int lane = tid & 63;

    for (int p = wave; p < cnt; p += 4) {
        const unsigned e = buckets[(size_t)chunk * CAP + p];
        const int tc = e & 31;
        const int n  = (e >> 5) & 31;
        const int b  = e >> 10;
        const float* __restrict__ xr = X + (size_t)b * VEC_DIM;

        float s = tile[tc][lane]       * xr[lane]
                + tile[tc][lane +  64] * xr[lane +  64]
                + tile[tc][lane + 128] * xr[lane + 128]
                + tile[tc][lane + 192] * xr[lane + 192];
        if (lane < VEC_DIM - 256)
            s += tile[tc][lane + 256] * xr[lane + 256];
#pragma unroll
        for (int off = 32; off > 0; off >>= 1)
            s += __shfl_down(s, off, 64);
        if (lane == 0) out[b * NUM_NOISE + n] = s;
    }
}

// ===========================================================================
// Fallback paths (smaller ws): R1 transpose path (needs 120 MB) and
// direct-gather path (needs none).
// ===========================================================================
#define TWORDS 32

__global__ __launch_bounds__(256) void transpose_kernel(
    const float* __restrict__ O, float* __restrict__ OT)
{
    __shared__ float tile[TWORDS * VEC_DIM];
    const int wBase = blockIdx.x * TWORDS;
    const int tid   = threadIdx.x;
    for (int idx = tid; idx < VEC_DIM * (TWORDS / 4); idx += 256) {
        const int d = idx >> 3;
        const int c = idx & 7;
        const float4 v = *reinterpret_cast<const float4*>(
            O + (size_t)d * NUM_WORDS + wBase + 4 * c);
        tile[(4 * c + 0) * VEC_DIM + d] = v.x;
        tile[(4 * c + 1) * VEC_DIM + d] = v.y;
        tile[(4 * c + 2) * VEC_DIM + d] = v.z;
        tile[(4 * c + 3) * VEC_DIM + d] = v.w;
    }
    __syncthreads();
    for (int idx = tid; idx < TWORDS * VEC_F4; idx += 256) {
        const int w = idx / VEC_F4;
        const int c = idx - w * VEC_F4;
        const float4 v = *reinterpret_cast<const float4*>(tile + w * VEC_DIM + 4 * c);
        *reinterpret_cast<float4*>(OT + (size_t)(wBase + w) * VEC_DIM + 4 * c) = v;
    }
}

__global__ __launch_bounds__(256) void pvdm_score_kernel(
    const int* __restrict__ context_ids, const int* __restrict__ doc_ids,
    const int* __restrict__ tn_ids, const float* __restrict__ D,
    const float* __restrict__ W, const float* __restrict__ OT,
    float* __restrict__ out)
{
    __shared__ float4 xs4[VEC_F4];
    const int b   = blockIdx.x;
    const int tid = threadIdx.x;
    if (tid < VEC_F4) {
        const int doc = doc_ids[b];
        float4 v = reinterpret_cast<const float4*>(D + (size_t)doc * VEC_DIM)[tid];
#pragma unroll
        for (int c = 0; c < NUM_CTX; ++c) {
            const int wd = context_ids[b * NUM_CTX + c];
            const float4 u =
                reinterpret_cast<const float4*>(W + (size_t)wd * VEC_DIM)[tid];
            v.x += u.x; v.y += u.y; v.z += u.z; v.w += u.w;
        }
        xs4[tid] = v;
    }
    __syncthreads();
    const int wave = tid >> 6;
    const int lane = tid & 63;
    const float4 xa = xs4[lane];
    float4 xb = make_float4(0.f, 0.f, 0.f, 0.f);
    if (lane < VEC_F4 - 64) xb = xs4[64 + lane];
    const int* __restrict__ tb = tn_ids + b * NUM_NOISE;
#pragma unroll
    for (int k = 0; k < 7; ++k) {
        const int n = wave + 4 * k;
        if (n < NUM_NOISE) {
            const int t = tb[n];
            const float4* __restrict__ row =
                reinterpret_cast<const float4*>(OT + (size_t)t * VEC_DIM);
            const float4 ra = row[lane];
            float s = ra.x * xa.x + ra.y * xa.y + ra.z * xa.z + ra.w * xa.w;
            if (lane < VEC_F4 - 64) {
                const float4 rb = row[64 + lane];
                s += rb.x * xb.x + rb.y * xb.y + rb.z * xb.z + rb.w * xb.w;
            }
#pragma unroll
            for (int off = 32; off > 0; off >>= 1)
                s += __shfl_down(s, off, 64);
            if (lane == 0) out[b * NUM_NOISE + n] = s;
        }
    }
}

__global__ __launch_bounds__(256) void pvdm_score_direct_kernel(
    const int* __restrict__ context_ids, const int* __restrict__ doc_ids,
    const int* __restrict__ tn_ids, const float* __restrict__ D,
    const float* __restrict__ W, const float* __restrict__ O,
    float* __restrict__ out)
{
    __shared__ float xs[VEC_DIM];
    const int b   = blockIdx.x;
    const int tid = threadIdx.x;
    const int doc = doc_ids[b];
    int ctx[NUM_CTX];
#pragma unroll
    for (int c = 0; c < NUM_CTX; ++c) ctx[c] = context_ids[b * NUM_CTX + c];
    for (int d = tid; d < VEC_DIM; d += 256) {
        float v = D[(size_t)doc * VEC_DIM + d];
#pragma unroll
        for (int c = 0; c < NUM_CTX; ++c)
            v += W[(size_t)ctx[c] * VEC_DIM + d];
        xs[d] = v;
    }
    __syncthreads();
    const int wave = tid >> 6;
    const int lane = tid & 63;
    for (int n = wave; n < NUM_NOISE; n += 4) {
        const int t = tn_ids[b * NUM_NOISE + n];
        float s = 0.0f;
        for (int d = lane; d < VEC_DIM; d += 64)
            s += xs[d] * O[(size_t)d * NUM_WORDS + t];
#pragma unroll
        for (int off = 32; off > 0; off >>= 1)
            s += __shfl_down(s, off, 64);
        if (lane == 0) out[b * NUM_NOISE + n] = s;
    }
}

extern "C" void kernel_launch(void* const* d_in, const int* in_sizes, int n_in,
                              void* d_out, int out_size, void* d_ws, size_t ws_size,
                              hipStream_t stream) {
    const int*   context_ids = (const int*)  d_in[0];
    const int*   doc_ids     = (const int*)  d_in[1];
    const int*   tn_ids      = (const int*)  d_in[2];
    const float* D           = (const float*)d_in[3];
    const float* W           = (const float*)d_in[4];
    const float* O           = (const float*)d_in[5];
    float*       out         = (float*)d_out;

    if (ws_size >= WS_NEEDED) {
        // Word-centric path: O read exactly once (120 MB), no transpose.
        char* ws = (char*)d_ws;
        float*    X        = (float*)   (ws + WS_X_OFF);
        int*      counters = (int*)     (ws + WS_CNT_OFF);
        unsigned* buckets  = (unsigned*)(ws + WS_BKT_OFF);

        zero_counters_kernel<<<(NCHUNK + 255) / 256, 256, 0, stream>>>(counters);
        build_scatter_kernel<<<BATCH_N, 128, 0, stream>>>(
            context_ids, doc_ids, tn_ids, D, W, X, counters, buckets);
        chunk_score_kernel<<<NCHUNK, 256, 0, stream>>>(
            O, X, counters, buckets, out);
    } else if (ws_size >= (size_t)NUM_WORDS * VEC_DIM * sizeof(float)) {
        float* OT = (float*)d_ws;
        transpose_kernel<<<NUM_WORDS / TWORDS, 256, 0, stream>>>(O, OT);
        pvdm_score_kernel<<<BATCH_N, 256, 0, stream>>>(
            context_ids, doc_ids, tn_ids, D, W, OT, out);
    } else {
        pvdm_score_direct_kernel<<<BATCH_N, 256, 0, stream>>>(
            context_ids, doc_ids, tn_ids, D, W, O, out);
    }
}